// Round 11
// baseline (611.121 us; speedup 1.0000x reference)
//
#include <hip/hip_runtime.h>

#define NN 20000
#define NE 100000
#define EPAD 100096   // NE padded up to multiple of 256
#define INF 16
#define HID 64

typedef __attribute__((ext_vector_type(8))) short short8;
typedef __attribute__((ext_vector_type(4))) float f32x4;

// scal layout (float indices); memset to 0 once per launch
#define SSW0 0     // sumw[3]
#define SRD0 16    // readout_unnorm[3][64]
#define HL0  256   // hl state slots [4][64] (slot k = hl after k LSTM steps)
#define CL0  512   // cl state slots [4][64]

__device__ inline float bf2f(unsigned short u) {
    union { unsigned u32; float f; } c; c.u32 = ((unsigned)u) << 16; return c.f;
}
__device__ inline unsigned short f2b(float f) {
    union { float f; unsigned u; } c; c.f = f;
    unsigned u = c.u;
    unsigned r = u + 0x7fffu + ((u >> 16) & 1u);
    return (unsigned short)(r >> 16);
}
__device__ inline float sigm(float x) { return 1.f / (1.f + expf(-x)); }
__device__ inline short8 s8zero() {
    short8 v;
    #pragma unroll
    for (int z = 0; z < 8; ++z) v[z] = 0;
    return v;
}
__device__ inline void gload_lds16(const void* g, void* l) {
    __builtin_amdgcn_global_load_lds(
        (const __attribute__((address_space(1))) unsigned*)g,
        (__attribute__((address_space(3))) unsigned*)l, 16, 0, 0);
}

__global__ void k_sentinel(float* out) { out[0] = 12345.0f; }

// ---------------- merged prologue: lin0 | deg-count | w2 transpose | b2t prep ----------------
// grid slices: [0,5000) lin0 ; [5000,5391) count ; [5391,5455) tr ; [5455,5471) prep
#define PRE_LIN0 5000
#define PRE_CNT  5391
#define PRE_TR   5455
#define PRE_ALL  5471
__global__ __launch_bounds__(256) void k_pre(
        const float* __restrict__ nfeat, const float* __restrict__ lw,
        const float* __restrict__ lb, float* __restrict__ X,
        unsigned short* __restrict__ Xb,
        const int* __restrict__ dst, int* __restrict__ icnt,
        const float* __restrict__ w2, unsigned short* __restrict__ w2t,
        const float* __restrict__ e2b, unsigned short* __restrict__ b2t) {
    __shared__ float ts[128][65];
    const int b = blockIdx.x, tid = threadIdx.x;
    if (b < PRE_LIN0) {
        // lin0 + relu (N*64 threads)
        int t = b * 256 + tid;
        int n = t >> 6, o = t & 63;
        float acc = lb[o];
        #pragma unroll
        for (int i = 0; i < INF; ++i) acc += nfeat[n * INF + i] * lw[i * HID + o];
        float v = fmaxf(acc, 0.f);
        X[t] = v;
        Xb[t] = f2b(v);
    } else if (b < PRE_CNT) {
        int e = (b - PRE_LIN0) * 256 + tid;
        if (e < NE) atomicAdd(&icnt[dst[e]], 1);
    } else if (b < PRE_TR) {
        // transpose e2_w -> w2t [4096][128] bf16, PRE-SWIZZLED
        // (16B slot s of row o stored at s ^ (o&7), so linear global_load_lds
        //  into LDS lands swizzled)
        int og0 = (b - PRE_CNT) * 64;
        for (int v = tid; v < 2048; v += 256) {
            int k = v >> 4, c4 = (v & 15) << 2;
            float4 val = *reinterpret_cast<const float4*>(&w2[(size_t)k * 4096 + og0 + c4]);
            ts[k][c4 + 0] = val.x; ts[k][c4 + 1] = val.y;
            ts[k][c4 + 2] = val.z; ts[k][c4 + 3] = val.w;
        }
        __syncthreads();
        int ogl = tid >> 2;                // o within block (0..63)
        int k0 = (tid & 3) * 32;           // 32 k per thread = 4 slots of 8
        unsigned short buf[32];
        #pragma unroll
        for (int j = 0; j < 32; ++j) buf[j] = f2b(ts[k0 + j][ogl]);
        size_t base = (size_t)(og0 + ogl) * 128;
        #pragma unroll
        for (int q = 0; q < 4; ++q) {
            int s = (tid & 3) * 4 + q;            // slot index 0..15
            int pos = (s ^ (ogl & 7)) * 8;        // swizzled short offset
            short8 pv;
            #pragma unroll
            for (int z = 0; z < 8; ++z) pv[z] = buf[q * 8 + z];
            *reinterpret_cast<short8*>(&w2t[base + pos]) = pv;
        }
    } else {
        int t = (b - PRE_TR) * 256 + tid;   // 4096
        int o = t >> 6, i = t & 63;
        b2t[o * 64 + i] = f2b(e2b[i * 64 + o]);
    }
}

// ---------------- exclusive prefix scan over cnt[NN] -> istart[NN+1] ----------------
__global__ void k_scan(const int* __restrict__ cnt, int* __restrict__ istart) {
    __shared__ int ps[1024];
    int t = threadIdx.x;
    const int CH = (NN + 1023) / 1024;
    int lo = t * CH, hi = (lo + CH < NN) ? lo + CH : NN;
    if (lo > NN) lo = NN;
    if (hi < lo) hi = lo;
    int s = 0;
    for (int i = lo; i < hi; ++i) s += cnt[i];
    ps[t] = s;
    __syncthreads();
    for (int off = 1; off < 1024; off <<= 1) {
        int v = (t >= off) ? ps[t - off] : 0;
        __syncthreads();
        ps[t] += v;
        __syncthreads();
    }
    int run = ps[t] - s;   // exclusive base
    for (int i = lo; i < hi; ++i) { istart[i] = run; run += cnt[i]; }
    if (t == 1023) istart[NN] = run;   // == E
}

// ---------------- scatter edges into dst-sorted order ----------------
__global__ void k_scatter(const int* __restrict__ src, const int* __restrict__ dst,
        const int* __restrict__ istart, int* __restrict__ cnt2,
        int* __restrict__ ssrc, int* __restrict__ sdst, int* __restrict__ spos, int E) {
    int e = blockIdx.x * blockDim.x + threadIdx.x;
    if (e >= E) return;
    int d = dst[e];
    int p = istart[d] + atomicAdd(&cnt2[d], 1);
    ssrc[p] = src[e];
    sdst[p] = d;
    spos[e] = p;
}

// ---------------- edge MLP layer 1 + relu -> bf16 (written at sorted pos) ----------------
__global__ __launch_bounds__(256) void k_e1(const float* __restrict__ efeat,
        const float* __restrict__ w, const float* __restrict__ b,
        const int* __restrict__ spos, unsigned short* __restrict__ h1b) {
    int t = blockIdx.x * 256 + threadIdx.x;   // E*128 threads
    int e = t >> 7, k = t & 127;
    float acc = b[k];
    #pragma unroll
    for (int i = 0; i < 5; ++i) acc += efeat[e * 5 + i] * w[i * 128 + k];
    h1b[(size_t)spos[e] * 128 + k] = f2b(fmaxf(acc, 0.f));
}

// ---------------- fused msg (+bias): 512 thr, 256 edges, o-split, shared slab ----------------
// Grid (EPAD/256, 2): block = 32 o-rows (y-half) x 256 sorted edges, 8 waves.
// Wave w: o-sub (w>>2)*16, e-quarter (w&3)*64. Per-wave inner loop identical to
// the verified r5 config; slab DMA/edge and barriers/edge HALVED.
__global__ __launch_bounds__(512, 4) void k_msg(
        const unsigned short* __restrict__ Xb,
        const unsigned short* __restrict__ h1b,
        const unsigned short* __restrict__ w2t,
        const unsigned short* __restrict__ b2t,
        const int* __restrict__ ssrc, const int* __restrict__ sdst,
        const int* __restrict__ istart, float* __restrict__ agg) {
    __shared__ __align__(16) char smem[54272];
    // [0,16384): slab dbuf 2x8KB ; [16384,53248): xeb [256][72] bf16 ; [53248,54272): sdst_s[256]
    unsigned short* xeb = (unsigned short*)(smem + 16384);
    int* sdst_s         = (int*)(smem + 53248);
    const int tid = threadIdx.x;
    const int e0 = blockIdx.x * 256;
    const int y  = blockIdx.y;          // o-half
    const int w = tid >> 6, l = tid & 63;
    const int wo_l = (w >> 2) * 16;     // o base within half (0 or 16)
    const int weq  = (w & 3) * 64;      // e base within block (0,64,128,192)
    const int l15 = l & 15, lh = l >> 4;

    // stage xeb (gathered Xb rows, sorted src) + sdst_s
    for (int v = tid; v < 2048; v += 512) {
        int row = v >> 3, c8 = (v & 7) << 3;
        int ee = e0 + row;
        short8 val = s8zero();
        if (ee < NE)
            val = *reinterpret_cast<const short8*>(&Xb[(size_t)ssrc[ee] * 64 + c8]);
        *reinterpret_cast<short8*>(&xeb[row * 72 + c8]) = val;
    }
    if (tid < 256) {
        int ee = e0 + tid;
        sdst_s[tid] = (ee < NE) ? sdst[ee] : NN;
    }

    // stage slab buf0 for i=0 (async DMA, linear; global already swizzled)
    // wave w stages its 1KB slice of the 8KB y-half slab
    gload_lds16((const char*)w2t + (size_t)y * 8192 + w * 1024 + l * 16,
                smem + w * 1024);

    // B fragments (h1, i-invariant, sorted edge rows)
    short8 bfr[4][4];
    #pragma unroll
    for (int ef = 0; ef < 4; ++ef) {
        const unsigned short* hp = &h1b[(size_t)(e0 + weq + ef * 16 + l15) * 128 + lh * 8];
        #pragma unroll
        for (int ks = 0; ks < 4; ++ks)
            bfr[ef][ks] = *reinterpret_cast<const short8*>(hp + ks * 32);
    }

    f32x4 acc[4];
    #pragma unroll
    for (int ef = 0; ef < 4; ++ef) acc[ef] = f32x4{0.f, 0.f, 0.f, 0.f};
    const f32x4 zero = f32x4{0.f, 0.f, 0.f, 0.f};

    __syncthreads();   // xeb + sdst_s + slab0 ready (drains vmcnt)

    const int r = wo_l + l15;          // o-row within half (0..31)
    const int sw = r & 7;
    int cur = 0;
    #pragma unroll 1
    for (int i = 0; i < 64; ++i) {
        // issue next slab DMA early (hides L2 latency under MFMA)
        if (i < 63) {
            gload_lds16((const char*)w2t + (size_t)(i + 1) * 16384 + (size_t)y * 8192
                            + w * 1024 + l * 16,
                        smem + (cur ^ 1) * 8192 + w * 1024);
        }
        float xv[4];
        #pragma unroll
        for (int ef = 0; ef < 4; ++ef)
            xv[ef] = bf2f(xeb[(weq + ef * 16 + l15) * 72 + i]);

        const unsigned short* rb = (const unsigned short*)(smem + cur * 8192) + r * 128;
        short8 a0 = *reinterpret_cast<const short8*>(&rb[((0 + lh) ^ sw) << 3]);
        short8 a1 = *reinterpret_cast<const short8*>(&rb[((4 + lh) ^ sw) << 3]);
        short8 a2 = *reinterpret_cast<const short8*>(&rb[((8 + lh) ^ sw) << 3]);
        short8 a3 = *reinterpret_cast<const short8*>(&rb[((12 + lh) ^ sw) << 3]);
        #pragma unroll
        for (int ef = 0; ef < 4; ++ef) {
            f32x4 t = __builtin_amdgcn_mfma_f32_16x16x32_bf16(a0, bfr[ef][0], zero, 0, 0, 0);
            t = __builtin_amdgcn_mfma_f32_16x16x32_bf16(a1, bfr[ef][1], t, 0, 0, 0);
            t = __builtin_amdgcn_mfma_f32_16x16x32_bf16(a2, bfr[ef][2], t, 0, 0, 0);
            t = __builtin_amdgcn_mfma_f32_16x16x32_bf16(a3, bfr[ef][3], t, 0, 0, 0);
            #pragma unroll
            for (int rr = 0; rr < 4; ++rr) acc[ef][rr] += xv[ef] * t[rr];
        }
        __syncthreads();   // next slab landed; all reads of cur done
        cur ^= 1;
    }

    // bias contribution: acc += B2T[o,i] @ Xb^T[i,e]  (K=64 over i)
    {
        const unsigned short* bp = &b2t[(y * 32 + r) * 64 + lh * 8];
        short8 ba0 = *reinterpret_cast<const short8*>(bp);
        short8 ba1 = *reinterpret_cast<const short8*>(bp + 32);
        #pragma unroll
        for (int ef = 0; ef < 4; ++ef) {
            int e = e0 + weq + ef * 16 + l15;
            int es = (e < NE) ? ssrc[e] : 0;
            const unsigned short* xp = &Xb[(size_t)es * 64 + lh * 8];
            short8 x0 = *reinterpret_cast<const short8*>(xp);
            short8 x1 = *reinterpret_cast<const short8*>(xp + 32);
            f32x4 tb = __builtin_amdgcn_mfma_f32_16x16x32_bf16(ba0, x0, zero, 0, 0, 0);
            tb = __builtin_amdgcn_mfma_f32_16x16x32_bf16(ba1, x1, tb, 0, 0, 0);
            #pragma unroll
            for (int rr = 0; rr < 4; ++rr) acc[ef][rr] += tb[rr];
        }
    }

    // epilogue: msg tile -> LDS [256 e][33 o], segmented reduce along sorted e
    __syncthreads();
    float* msgL = (float*)smem;   // 256*33*4 = 33792 B (sdst_s at 53248 preserved)
    #pragma unroll
    for (int ef = 0; ef < 4; ++ef)
        #pragma unroll
        for (int rr = 0; rr < 4; ++rr)
            msgL[(weq + ef * 16 + l15) * 33 + (wo_l + lh * 4 + rr)] = acc[ef][rr];
    __syncthreads();

    if (tid < 256) {
        int o = tid & 31, win = tid >> 5;     // 8 windows x 32 edges
        int base = win << 5;
        int lo = e0 + base, hi = lo + 32;
        int cn = -1; float s = 0.f;
        for (int e2 = base; e2 < base + 32; ++e2) {
            int n = sdst_s[e2];
            if (n != cn) {
                if (cn >= 0 && cn < NN) {
                    int st = istart[cn], en = istart[cn + 1];
                    if (st >= lo && en <= hi) agg[(size_t)cn * 64 + y * 32 + o] = s;
                    else atomicAdd(&agg[(size_t)cn * 64 + y * 32 + o], s);
                }
                cn = n; s = 0.f;
            }
            s += msgL[e2 * 33 + o];
        }
        if (cn >= 0 && cn < NN) {
            int st = istart[cn], en = istart[cn + 1];
            if (st >= lo && en <= hi) agg[(size_t)cn * 64 + y * 32 + o] = s;
            else atomicAdd(&agg[(size_t)cn * 64 + y * 32 + o], s);
        }
    }
}

// ---------------- NNConv bias+relu + GRU cell, 16 nodes/block; re-zeros agg ----------------
__global__ __launch_bounds__(256) void k_gru(float* __restrict__ agg,
        const int* __restrict__ istart, const float* __restrict__ cbias,
        const float* __restrict__ wih, const float* __restrict__ whh,
        const float* __restrict__ bih, const float* __restrict__ bhh,
        float* __restrict__ X, unsigned short* __restrict__ Xb,
        float* __restrict__ Xout, int zero_agg) {
    __shared__ float ms[16][65], hs[16][65];
    int tid = threadIdx.x;
    int l = tid & 63, g = tid >> 6;
    int nb = blockIdx.x * 16;
    for (int v = tid; v < 1024; v += 256) {
        int row = v >> 6, c = v & 63;
        int n = nb + row;
        size_t idx = (size_t)n * 64 + c;
        float dv = fmaxf((float)(istart[n + 1] - istart[n]), 1.f);
        ms[row][c] = fmaxf(agg[idx] / dv + cbias[c], 0.f);
        hs[row][c] = X[idx];
        if (zero_agg) agg[idx] = 0.f;   // fold next-round memset into this pass
    }
    __syncthreads();
    float gr[4], gz[4], gn[4], hr[4], hz[4], hn[4];
    float b0 = bih[l], b1 = bih[64 + l], b2 = bih[128 + l];
    float c0 = bhh[l], c1 = bhh[64 + l], c2 = bhh[128 + l];
    #pragma unroll
    for (int j = 0; j < 4; ++j) {
        gr[j] = b0; gz[j] = b1; gn[j] = b2;
        hr[j] = c0; hz[j] = c1; hn[j] = c2;
    }
    #pragma unroll 4
    for (int i = 0; i < 64; ++i) {
        float wr = wih[i * 192 + l], wz = wih[i * 192 + 64 + l], wn = wih[i * 192 + 128 + l];
        float vr = whh[i * 192 + l], vz = whh[i * 192 + 64 + l], vn = whh[i * 192 + 128 + l];
        #pragma unroll
        for (int j = 0; j < 4; ++j) {
            float mi = ms[g * 4 + j][i], hi = hs[g * 4 + j][i];
            gr[j] += mi * wr; gz[j] += mi * wz; gn[j] += mi * wn;
            hr[j] += hi * vr; hz[j] += hi * vz; hn[j] += hi * vn;
        }
    }
    #pragma unroll
    for (int j = 0; j < 4; ++j) {
        int n = nb + g * 4 + j;
        float h = hs[g * 4 + j][l];
        float r = sigm(gr[j] + hr[j]);
        float z = sigm(gz[j] + hz[j]);
        float nn2 = tanhf(gn[j] + r * hn[j]);
        float newh = (1.f - z) * nn2 + z * h;
        X[(size_t)n * 64 + l] = newh;
        Xb[(size_t)n * 64 + l] = f2b(newh);
        if (Xout) Xout[(size_t)n * 64 + l] = newh;
    }
}

// ---------------- fused Set2Set step: inline LSTM (redundant per block) + pool ----------------
// Versioned hl/cl state slots make redundant identical writes benign.
__global__ __launch_bounds__(256) void k_pool(const float* __restrict__ X,
        const float* __restrict__ lwih, const float* __restrict__ lwhh,
        const float* __restrict__ lbih, const float* __restrict__ lbhh,
        float* __restrict__ scal, int it) {
    __shared__ float qsin[128];
    __shared__ float gg[256];
    __shared__ float qsh[64];
    __shared__ float accs[4][65];
    __shared__ float sws[4];
    int t = threadIdx.x;
    // q_star input = [hl^it, readout^{it-1}/ssw^{it-1}] (zeros at it=0)
    if (t < 128) {
        float v;
        if (t < 64) v = scal[HL0 + it * 64 + t];
        else        v = (it > 0) ? scal[SRD0 + (it - 1) * 64 + (t - 64)] / scal[SSW0 + it - 1] : 0.f;
        qsin[t] = v;
    }
    __syncthreads();
    // LSTM gates (torch order i,f,g,o)
    float acc = lbih[t] + lbhh[t];
    for (int i = 0; i < 128; ++i) acc += qsin[i] * lwih[i * 256 + t];
    for (int i = 0; i < 64; ++i)  acc += qsin[i] * lwhh[i * 256 + t];
    gg[t] = acc;
    __syncthreads();
    if (t < 64) {
        float ig = sigm(gg[t]), fg = sigm(gg[64 + t]);
        float g2 = tanhf(gg[128 + t]), og = sigm(gg[192 + t]);
        float cl = fg * scal[CL0 + it * 64 + t] + ig * g2;
        float hl = og * tanhf(cl);
        scal[CL0 + (it + 1) * 64 + t] = cl;   // identical across blocks: benign
        scal[HL0 + (it + 1) * 64 + t] = hl;
        qsh[t] = hl;
    }
    __syncthreads();
    // attention pool
    int w = t >> 6, l = t & 63;
    float q = qsh[l];
    int gw = blockIdx.x * 4 + w;      // 512 waves total
    float pacc = 0.f, sw = 0.f;
    for (int n = gw; n < NN; n += 512) {
        float xl = X[(size_t)n * 64 + l];
        float v = xl * q;
        #pragma unroll
        for (int off = 32; off; off >>= 1) v += __shfl_xor(v, off, 64);
        float wt = expf(v);
        pacc += wt * xl;
        sw += wt;
    }
    accs[w][l] = pacc;
    if (l == 0) sws[w] = sw;
    __syncthreads();
    if (w == 0) {
        float a = accs[0][l] + accs[1][l] + accs[2][l] + accs[3][l];
        atomicAdd(&scal[SRD0 + it * 64 + l], a);
        if (l == 0) atomicAdd(&scal[SSW0 + it], sws[0] + sws[1] + sws[2] + sws[3]);
    }
}

// ---------------- final q_star write ----------------
__global__ void k_fin(const float* __restrict__ scal, float* __restrict__ dq) {
    int t = threadIdx.x;  // 128
    float v;
    if (t < 64) v = scal[HL0 + 3 * 64 + t];
    else        v = scal[SRD0 + 2 * 64 + (t - 64)] / scal[SSW0 + 2];
    dq[t] = v;
}

extern "C" void kernel_launch(void* const* d_in, const int* in_sizes, int n_in,
                              void* d_out, int out_size, void* d_ws, size_t ws_size,
                              hipStream_t stream) {
    const float* nfeat   = (const float*)d_in[0];
    const float* efeat   = (const float*)d_in[1];
    const int*   src     = (const int*)d_in[2];
    const int*   dst     = (const int*)d_in[3];
    const float* lin0_w  = (const float*)d_in[4];
    const float* lin0_b  = (const float*)d_in[5];
    const float* e1_w    = (const float*)d_in[6];
    const float* e1_b    = (const float*)d_in[7];
    const float* e2_w    = (const float*)d_in[8];
    const float* e2_b    = (const float*)d_in[9];
    const float* conv_b  = (const float*)d_in[10];
    const float* gwih    = (const float*)d_in[11];
    const float* gwhh    = (const float*)d_in[12];
    const float* gbih    = (const float*)d_in[13];
    const float* gbhh    = (const float*)d_in[14];
    const float* lwih    = (const float*)d_in[15];
    const float* lwhh    = (const float*)d_in[16];
    const float* lbih    = (const float*)d_in[17];
    const float* lbhh    = (const float*)d_in[18];

    const int N = NN, E = NE;

    size_t off = 0;
    auto take = [&](size_t bytes) { size_t o = off; off = (off + bytes + 255) & ~(size_t)255; return o; };
    size_t oX    = take((size_t)N * 64 * 4);
    size_t oAgg  = take((size_t)N * 64 * 4);
    size_t oScal = take(4096);
    size_t oH1   = take((size_t)EPAD * 128 * 2);
    size_t oW2T  = take((size_t)4096 * 128 * 2);
    size_t oXb   = take((size_t)N * 64 * 2);
    size_t oB2T  = take((size_t)64 * 64 * 2);
    size_t oIst  = take((size_t)(N + 1) * 4);
    size_t oIc1  = take((size_t)N * 4);
    size_t oIc2  = take((size_t)N * 4);
    size_t oSs   = take((size_t)E * 4);
    size_t oSd   = take((size_t)E * 4);
    size_t oSp   = take((size_t)E * 4);
    size_t needed = off;

    float* outp = (float*)d_out;
    if (ws_size < needed) {
        k_sentinel<<<1, 1, 0, stream>>>(outp);
        return;
    }

    char* wsb = (char*)d_ws;
    float* X    = (float*)(wsb + oX);
    float* agg  = (float*)(wsb + oAgg);
    float* scal = (float*)(wsb + oScal);
    unsigned short* h1b = (unsigned short*)(wsb + oH1);
    unsigned short* w2t = (unsigned short*)(wsb + oW2T);
    unsigned short* Xb  = (unsigned short*)(wsb + oXb);
    unsigned short* b2t = (unsigned short*)(wsb + oB2T);
    int* istart = (int*)(wsb + oIst);
    int* icnt   = (int*)(wsb + oIc1);
    int* icnt2  = (int*)(wsb + oIc2);
    int* ssrc   = (int*)(wsb + oSs);
    int* sdst   = (int*)(wsb + oSd);
    int* spos   = (int*)(wsb + oSp);

    hipMemsetAsync(scal, 0, 4096, stream);
    hipMemsetAsync(icnt, 0, (size_t)N * 4, stream);
    hipMemsetAsync(icnt2, 0, (size_t)N * 4, stream);
    hipMemsetAsync(agg, 0, (size_t)N * 64 * 4, stream);
    hipMemsetAsync(h1b + (size_t)E * 128, 0, (size_t)(EPAD - E) * 128 * 2, stream);

    k_pre<<<PRE_ALL, 256, 0, stream>>>(nfeat, lin0_w, lin0_b, X, Xb,
                                       dst, icnt, e2_w, w2t, e2_b, b2t);
    k_scan<<<1, 1024, 0, stream>>>(icnt, istart);
    k_scatter<<<(E + 255) / 256, 256, 0, stream>>>(src, dst, istart, icnt2, ssrc, sdst, spos, E);
    k_e1<<<(E * 128) / 256, 256, 0, stream>>>(efeat, e1_w, e1_b, spos, h1b);

    for (int r = 0; r < 3; ++r) {
        k_msg<<<dim3(EPAD / 256, 2), 512, 0, stream>>>(Xb, h1b, w2t, b2t, ssrc, sdst, istart, agg);
        k_gru<<<N / 16, 256, 0, stream>>>(agg, istart, conv_b, gwih, gwhh, gbih, gbhh,
                                          X, Xb, (r == 2) ? (outp + 128) : nullptr,
                                          (r < 2) ? 1 : 0);
    }

    for (int it = 0; it < 3; ++it) {
        k_pool<<<128, 256, 0, stream>>>(X, lwih, lwhh, lbih, lbhh, scal, it);
    }
    k_fin<<<1, 128, 0, stream>>>(scal, outp);
}

// Round 12
// 577.819 us; speedup vs baseline: 1.0576x; 1.0576x over previous
//
#include <hip/hip_runtime.h>

#define NN 20000
#define NE 100000
#define EPAD 100096   // NE padded up to multiple of 128
#define INF 16
#define HID 64

typedef __attribute__((ext_vector_type(8))) short short8;
typedef __attribute__((ext_vector_type(4))) float f32x4;

// scal layout (float indices); memset to 0 once per launch
#define SSW0 0     // sumw[3]
#define SRD0 16    // readout_unnorm[3][64]
#define HL0  256   // hl state slots [4][64] (slot k = hl after k LSTM steps)
#define CL0  512   // cl state slots [4][64]

__device__ inline float bf2f(unsigned short u) {
    union { unsigned u32; float f; } c; c.u32 = ((unsigned)u) << 16; return c.f;
}
__device__ inline unsigned short f2b(float f) {
    union { float f; unsigned u; } c; c.f = f;
    unsigned u = c.u;
    unsigned r = u + 0x7fffu + ((u >> 16) & 1u);
    return (unsigned short)(r >> 16);
}
__device__ inline float sigm(float x) { return 1.f / (1.f + expf(-x)); }
__device__ inline short8 s8zero() {
    short8 v;
    #pragma unroll
    for (int z = 0; z < 8; ++z) v[z] = 0;
    return v;
}
__device__ inline void gload_lds16(const void* g, void* l) {
    __builtin_amdgcn_global_load_lds(
        (const __attribute__((address_space(1))) unsigned*)g,
        (__attribute__((address_space(3))) unsigned*)l, 16, 0, 0);
}

__global__ void k_sentinel(float* out) { out[0] = 12345.0f; }

// ---------------- merged prologue: lin0 | deg-count | w2 transpose | b2t prep ----------------
// grid slices: [0,5000) lin0 ; [5000,5391) count ; [5391,5455) tr ; [5455,5471) prep
#define PRE_LIN0 5000
#define PRE_CNT  5391
#define PRE_TR   5455
#define PRE_ALL  5471
__global__ __launch_bounds__(256) void k_pre(
        const float* __restrict__ nfeat, const float* __restrict__ lw,
        const float* __restrict__ lb, float* __restrict__ X,
        unsigned short* __restrict__ Xb,
        const int* __restrict__ dst, int* __restrict__ icnt,
        const float* __restrict__ w2, unsigned short* __restrict__ w2t,
        const float* __restrict__ e2b, unsigned short* __restrict__ b2t) {
    __shared__ float ts[128][65];
    const int b = blockIdx.x, tid = threadIdx.x;
    if (b < PRE_LIN0) {
        // lin0 + relu (N*64 threads)
        int t = b * 256 + tid;
        int n = t >> 6, o = t & 63;
        float acc = lb[o];
        #pragma unroll
        for (int i = 0; i < INF; ++i) acc += nfeat[n * INF + i] * lw[i * HID + o];
        float v = fmaxf(acc, 0.f);
        X[t] = v;
        Xb[t] = f2b(v);
    } else if (b < PRE_CNT) {
        int e = (b - PRE_LIN0) * 256 + tid;
        if (e < NE) atomicAdd(&icnt[dst[e]], 1);
    } else if (b < PRE_TR) {
        // transpose e2_w -> w2t [4096][128] bf16, PRE-SWIZZLED
        // (16B slot s of row o stored at s ^ (o&7), so linear global_load_lds
        //  into LDS lands swizzled)
        int og0 = (b - PRE_CNT) * 64;
        for (int v = tid; v < 2048; v += 256) {
            int k = v >> 4, c4 = (v & 15) << 2;
            float4 val = *reinterpret_cast<const float4*>(&w2[(size_t)k * 4096 + og0 + c4]);
            ts[k][c4 + 0] = val.x; ts[k][c4 + 1] = val.y;
            ts[k][c4 + 2] = val.z; ts[k][c4 + 3] = val.w;
        }
        __syncthreads();
        int ogl = tid >> 2;                // o within block (0..63)
        int k0 = (tid & 3) * 32;           // 32 k per thread = 4 slots of 8
        unsigned short buf[32];
        #pragma unroll
        for (int j = 0; j < 32; ++j) buf[j] = f2b(ts[k0 + j][ogl]);
        size_t base = (size_t)(og0 + ogl) * 128;
        #pragma unroll
        for (int q = 0; q < 4; ++q) {
            int s = (tid & 3) * 4 + q;            // slot index 0..15
            int pos = (s ^ (ogl & 7)) * 8;        // swizzled short offset
            short8 pv;
            #pragma unroll
            for (int z = 0; z < 8; ++z) pv[z] = buf[q * 8 + z];
            *reinterpret_cast<short8*>(&w2t[base + pos]) = pv;
        }
    } else {
        int t = (b - PRE_TR) * 256 + tid;   // 4096
        int o = t >> 6, i = t & 63;
        b2t[o * 64 + i] = f2b(e2b[i * 64 + o]);
    }
}

// ---------------- exclusive prefix scan over cnt[NN] -> istart[NN+1] ----------------
__global__ void k_scan(const int* __restrict__ cnt, int* __restrict__ istart) {
    __shared__ int ps[1024];
    int t = threadIdx.x;
    const int CH = (NN + 1023) / 1024;
    int lo = t * CH, hi = (lo + CH < NN) ? lo + CH : NN;
    if (lo > NN) lo = NN;
    if (hi < lo) hi = lo;
    int s = 0;
    for (int i = lo; i < hi; ++i) s += cnt[i];
    ps[t] = s;
    __syncthreads();
    for (int off = 1; off < 1024; off <<= 1) {
        int v = (t >= off) ? ps[t - off] : 0;
        __syncthreads();
        ps[t] += v;
        __syncthreads();
    }
    int run = ps[t] - s;   // exclusive base
    for (int i = lo; i < hi; ++i) { istart[i] = run; run += cnt[i]; }
    if (t == 1023) istart[NN] = run;   // == E
}

// ---------------- scatter edges into dst-sorted order ----------------
__global__ void k_scatter(const int* __restrict__ src, const int* __restrict__ dst,
        const int* __restrict__ istart, int* __restrict__ cnt2,
        int* __restrict__ ssrc, int* __restrict__ sdst, int* __restrict__ spos, int E) {
    int e = blockIdx.x * blockDim.x + threadIdx.x;
    if (e >= E) return;
    int d = dst[e];
    int p = istart[d] + atomicAdd(&cnt2[d], 1);
    ssrc[p] = src[e];
    sdst[p] = d;
    spos[e] = p;
}

// ---------------- edge MLP layer 1 + relu -> bf16 (written at sorted pos) ----------------
__global__ __launch_bounds__(256) void k_e1(const float* __restrict__ efeat,
        const float* __restrict__ w, const float* __restrict__ b,
        const int* __restrict__ spos, unsigned short* __restrict__ h1b) {
    int t = blockIdx.x * 256 + threadIdx.x;   // E*128 threads
    int e = t >> 7, k = t & 127;
    float acc = b[k];
    #pragma unroll
    for (int i = 0; i < 5; ++i) acc += efeat[e * 5 + i] * w[i * 128 + k];
    h1b[(size_t)spos[e] * 128 + k] = f2b(fmaxf(acc, 0.f));
}

// ---------------- fused msg (+bias), o-split, gload_lds dbuf, seg-reduce ----------------
// Grid (EPAD/128, 2): block = 32 o-rows (y-half) x 128 sorted edges.
// 4 waves: wave w -> o-sub (w>>1)*16, e-half (w&1)*64. i-loop 0..63.
// (round-5 verified config: 135 us, VGPR 64, no spill) -- DO NOT RESTRUCTURE
__global__ __launch_bounds__(256, 4) void k_msg(
        const unsigned short* __restrict__ Xb,
        const unsigned short* __restrict__ h1b,
        const unsigned short* __restrict__ w2t,
        const unsigned short* __restrict__ b2t,
        const int* __restrict__ ssrc, const int* __restrict__ sdst,
        const int* __restrict__ istart, float* __restrict__ agg) {
    __shared__ __align__(16) char smem[35328];
    // [0,16384): slab dbuf 2x8KB ; [16384,34816): xeb [128][72] bf16 ; [34816,35328): sdst_s
    unsigned short* xeb = (unsigned short*)(smem + 16384);
    int* sdst_s         = (int*)(smem + 34816);
    const int tid = threadIdx.x;
    const int e0 = blockIdx.x * 128;
    const int y  = blockIdx.y;          // o-half
    const int w = tid >> 6, l = tid & 63;
    const int wo_l = (w >> 1) * 16;     // o base within half (0 or 16)
    const int weh  = (w & 1) * 64;      // e base within block (0 or 64)
    const int l15 = l & 15, lh = l >> 4;

    // stage xeb (gathered Xb rows, sorted src) + sdst_s
    for (int v = tid; v < 1024; v += 256) {
        int row = v >> 3, c8 = (v & 7) << 3;
        int ee = e0 + row;
        short8 val = s8zero();
        if (ee < NE)
            val = *reinterpret_cast<const short8*>(&Xb[(size_t)ssrc[ee] * 64 + c8]);
        *reinterpret_cast<short8*>(&xeb[row * 72 + c8]) = val;
    }
    if (tid < 128) {
        int ee = e0 + tid;
        sdst_s[tid] = (ee < NE) ? sdst[ee] : NN;
    }

    // stage slab buf0 for i=0 (async DMA, linear; global already swizzled)
    {
        const char* g0 = (const char*)w2t + (size_t)y * 8192;
        gload_lds16(g0 + w * 2048 + l * 16, smem + w * 2048);
        gload_lds16(g0 + w * 2048 + 1024 + l * 16, smem + w * 2048 + 1024);
    }

    // B fragments (h1, i-invariant, sorted edge rows)
    short8 bfr[4][4];
    #pragma unroll
    for (int ef = 0; ef < 4; ++ef) {
        const unsigned short* hp = &h1b[(size_t)(e0 + weh + ef * 16 + l15) * 128 + lh * 8];
        #pragma unroll
        for (int ks = 0; ks < 4; ++ks)
            bfr[ef][ks] = *reinterpret_cast<const short8*>(hp + ks * 32);
    }

    f32x4 acc[4];
    #pragma unroll
    for (int ef = 0; ef < 4; ++ef) acc[ef] = f32x4{0.f, 0.f, 0.f, 0.f};
    const f32x4 zero = f32x4{0.f, 0.f, 0.f, 0.f};

    __syncthreads();   // xeb + sdst_s + slab0 ready (drains vmcnt)

    const int r = wo_l + l15;          // o-row within half (0..31)
    const int sw = r & 7;
    int cur = 0;
    #pragma unroll 1
    for (int i = 0; i < 64; ++i) {
        // issue next slab DMA early (hides L2 latency under MFMA)
        if (i < 63) {
            const char* g = (const char*)w2t + (size_t)(i + 1) * 16384 + (size_t)y * 8192;
            char* dbase = smem + (cur ^ 1) * 8192;
            gload_lds16(g + w * 2048 + l * 16, dbase + w * 2048);
            gload_lds16(g + w * 2048 + 1024 + l * 16, dbase + w * 2048 + 1024);
        }
        float xv[4];
        #pragma unroll
        for (int ef = 0; ef < 4; ++ef)
            xv[ef] = bf2f(xeb[(weh + ef * 16 + l15) * 72 + i]);

        const unsigned short* rb = (const unsigned short*)(smem + cur * 8192) + r * 128;
        short8 a0 = *reinterpret_cast<const short8*>(&rb[((0 + lh) ^ sw) << 3]);
        short8 a1 = *reinterpret_cast<const short8*>(&rb[((4 + lh) ^ sw) << 3]);
        short8 a2 = *reinterpret_cast<const short8*>(&rb[((8 + lh) ^ sw) << 3]);
        short8 a3 = *reinterpret_cast<const short8*>(&rb[((12 + lh) ^ sw) << 3]);
        #pragma unroll
        for (int ef = 0; ef < 4; ++ef) {
            f32x4 t = __builtin_amdgcn_mfma_f32_16x16x32_bf16(a0, bfr[ef][0], zero, 0, 0, 0);
            t = __builtin_amdgcn_mfma_f32_16x16x32_bf16(a1, bfr[ef][1], t, 0, 0, 0);
            t = __builtin_amdgcn_mfma_f32_16x16x32_bf16(a2, bfr[ef][2], t, 0, 0, 0);
            t = __builtin_amdgcn_mfma_f32_16x16x32_bf16(a3, bfr[ef][3], t, 0, 0, 0);
            #pragma unroll
            for (int rr = 0; rr < 4; ++rr) acc[ef][rr] += xv[ef] * t[rr];
        }
        __syncthreads();   // next slab landed; all reads of cur done
        cur ^= 1;
    }

    // bias contribution: acc += B2T[o,i] @ Xb^T[i,e]  (K=64 over i)
    {
        const unsigned short* bp = &b2t[(y * 32 + r) * 64 + lh * 8];
        short8 ba0 = *reinterpret_cast<const short8*>(bp);
        short8 ba1 = *reinterpret_cast<const short8*>(bp + 32);
        #pragma unroll
        for (int ef = 0; ef < 4; ++ef) {
            int e = e0 + weh + ef * 16 + l15;
            int es = (e < NE) ? ssrc[e] : 0;
            const unsigned short* xp = &Xb[(size_t)es * 64 + lh * 8];
            short8 x0 = *reinterpret_cast<const short8*>(xp);
            short8 x1 = *reinterpret_cast<const short8*>(xp + 32);
            f32x4 tb = __builtin_amdgcn_mfma_f32_16x16x32_bf16(ba0, x0, zero, 0, 0, 0);
            tb = __builtin_amdgcn_mfma_f32_16x16x32_bf16(ba1, x1, tb, 0, 0, 0);
            #pragma unroll
            for (int rr = 0; rr < 4; ++rr) acc[ef][rr] += tb[rr];
        }
    }

    // epilogue: msg tile -> LDS [128 e][33 o], segmented reduce along sorted e
    __syncthreads();
    float* msgL = (float*)smem;
    #pragma unroll
    for (int ef = 0; ef < 4; ++ef)
        #pragma unroll
        for (int rr = 0; rr < 4; ++rr)
            msgL[(weh + ef * 16 + l15) * 33 + (wo_l + lh * 4 + rr)] = acc[ef][rr];
    __syncthreads();

    if (tid < 128) {
        int o = tid & 31, win = tid >> 5;     // 4 windows x 32 edges
        int base = win << 5;
        int lo = e0 + base, hi = lo + 32;
        int cn = -1; float s = 0.f;
        for (int e2 = base; e2 < base + 32; ++e2) {
            int n = sdst_s[e2];
            if (n != cn) {
                if (cn >= 0 && cn < NN) {
                    int st = istart[cn], en = istart[cn + 1];
                    if (st >= lo && en <= hi) agg[(size_t)cn * 64 + y * 32 + o] = s;
                    else atomicAdd(&agg[(size_t)cn * 64 + y * 32 + o], s);
                }
                cn = n; s = 0.f;
            }
            s += msgL[e2 * 33 + o];
        }
        if (cn >= 0 && cn < NN) {
            int st = istart[cn], en = istart[cn + 1];
            if (st >= lo && en <= hi) agg[(size_t)cn * 64 + y * 32 + o] = s;
            else atomicAdd(&agg[(size_t)cn * 64 + y * 32 + o], s);
        }
    }
}

// ---------------- NNConv bias+relu + GRU cell, 16 nodes/block; re-zeros agg ----------------
__global__ __launch_bounds__(256) void k_gru(float* __restrict__ agg,
        const int* __restrict__ istart, const float* __restrict__ cbias,
        const float* __restrict__ wih, const float* __restrict__ whh,
        const float* __restrict__ bih, const float* __restrict__ bhh,
        float* __restrict__ X, unsigned short* __restrict__ Xb,
        float* __restrict__ Xout, int zero_agg) {
    __shared__ float ms[16][65], hs[16][65];
    int tid = threadIdx.x;
    int l = tid & 63, g = tid >> 6;
    int nb = blockIdx.x * 16;
    for (int v = tid; v < 1024; v += 256) {
        int row = v >> 6, c = v & 63;
        int n = nb + row;
        size_t idx = (size_t)n * 64 + c;
        float dv = fmaxf((float)(istart[n + 1] - istart[n]), 1.f);
        ms[row][c] = fmaxf(agg[idx] / dv + cbias[c], 0.f);
        hs[row][c] = X[idx];
        if (zero_agg) agg[idx] = 0.f;   // fold next-round memset into this pass
    }
    __syncthreads();
    float gr[4], gz[4], gn[4], hr[4], hz[4], hn[4];
    float b0 = bih[l], b1 = bih[64 + l], b2 = bih[128 + l];
    float c0 = bhh[l], c1 = bhh[64 + l], c2 = bhh[128 + l];
    #pragma unroll
    for (int j = 0; j < 4; ++j) {
        gr[j] = b0; gz[j] = b1; gn[j] = b2;
        hr[j] = c0; hz[j] = c1; hn[j] = c2;
    }
    #pragma unroll 4
    for (int i = 0; i < 64; ++i) {
        float wr = wih[i * 192 + l], wz = wih[i * 192 + 64 + l], wn = wih[i * 192 + 128 + l];
        float vr = whh[i * 192 + l], vz = whh[i * 192 + 64 + l], vn = whh[i * 192 + 128 + l];
        #pragma unroll
        for (int j = 0; j < 4; ++j) {
            float mi = ms[g * 4 + j][i], hi = hs[g * 4 + j][i];
            gr[j] += mi * wr; gz[j] += mi * wz; gn[j] += mi * wn;
            hr[j] += hi * vr; hz[j] += hi * vz; hn[j] += hi * vn;
        }
    }
    #pragma unroll
    for (int j = 0; j < 4; ++j) {
        int n = nb + g * 4 + j;
        float h = hs[g * 4 + j][l];
        float r = sigm(gr[j] + hr[j]);
        float z = sigm(gz[j] + hz[j]);
        float nn2 = tanhf(gn[j] + r * hn[j]);
        float newh = (1.f - z) * nn2 + z * h;
        X[(size_t)n * 64 + l] = newh;
        Xb[(size_t)n * 64 + l] = f2b(newh);
        if (Xout) Xout[(size_t)n * 64 + l] = newh;
    }
}

// ---------------- fused Set2Set step: inline LSTM (redundant per block) + pool ----------------
// Versioned hl/cl state slots make redundant identical writes benign.
__global__ __launch_bounds__(256) void k_pool(const float* __restrict__ X,
        const float* __restrict__ lwih, const float* __restrict__ lwhh,
        const float* __restrict__ lbih, const float* __restrict__ lbhh,
        float* __restrict__ scal, int it) {
    __shared__ float qsin[128];
    __shared__ float gg[256];
    __shared__ float qsh[64];
    __shared__ float accs[4][65];
    __shared__ float sws[4];
    int t = threadIdx.x;
    // q_star input = [hl^it, readout^{it-1}/ssw^{it-1}] (zeros at it=0)
    if (t < 128) {
        float v;
        if (t < 64) v = scal[HL0 + it * 64 + t];
        else        v = (it > 0) ? scal[SRD0 + (it - 1) * 64 + (t - 64)] / scal[SSW0 + it - 1] : 0.f;
        qsin[t] = v;
    }
    __syncthreads();
    // LSTM gates (torch order i,f,g,o)
    float acc = lbih[t] + lbhh[t];
    for (int i = 0; i < 128; ++i) acc += qsin[i] * lwih[i * 256 + t];
    for (int i = 0; i < 64; ++i)  acc += qsin[i] * lwhh[i * 256 + t];
    gg[t] = acc;
    __syncthreads();
    if (t < 64) {
        float ig = sigm(gg[t]), fg = sigm(gg[64 + t]);
        float g2 = tanhf(gg[128 + t]), og = sigm(gg[192 + t]);
        float cl = fg * scal[CL0 + it * 64 + t] + ig * g2;
        float hl = og * tanhf(cl);
        scal[CL0 + (it + 1) * 64 + t] = cl;   // identical across blocks: benign
        scal[HL0 + (it + 1) * 64 + t] = hl;
        qsh[t] = hl;
    }
    __syncthreads();
    // attention pool
    int w = t >> 6, l = t & 63;
    float q = qsh[l];
    int gw = blockIdx.x * 4 + w;      // 512 waves total
    float pacc = 0.f, sw = 0.f;
    for (int n = gw; n < NN; n += 512) {
        float xl = X[(size_t)n * 64 + l];
        float v = xl * q;
        #pragma unroll
        for (int off = 32; off; off >>= 1) v += __shfl_xor(v, off, 64);
        float wt = expf(v);
        pacc += wt * xl;
        sw += wt;
    }
    accs[w][l] = pacc;
    if (l == 0) sws[w] = sw;
    __syncthreads();
    if (w == 0) {
        float a = accs[0][l] + accs[1][l] + accs[2][l] + accs[3][l];
        atomicAdd(&scal[SRD0 + it * 64 + l], a);
        if (l == 0) atomicAdd(&scal[SSW0 + it], sws[0] + sws[1] + sws[2] + sws[3]);
    }
}

// ---------------- final q_star write ----------------
__global__ void k_fin(const float* __restrict__ scal, float* __restrict__ dq) {
    int t = threadIdx.x;  // 128
    float v;
    if (t < 64) v = scal[HL0 + 3 * 64 + t];
    else        v = scal[SRD0 + 2 * 64 + (t - 64)] / scal[SSW0 + 2];
    dq[t] = v;
}

extern "C" void kernel_launch(void* const* d_in, const int* in_sizes, int n_in,
                              void* d_out, int out_size, void* d_ws, size_t ws_size,
                              hipStream_t stream) {
    const float* nfeat   = (const float*)d_in[0];
    const float* efeat   = (const float*)d_in[1];
    const int*   src     = (const int*)d_in[2];
    const int*   dst     = (const int*)d_in[3];
    const float* lin0_w  = (const float*)d_in[4];
    const float* lin0_b  = (const float*)d_in[5];
    const float* e1_w    = (const float*)d_in[6];
    const float* e1_b    = (const float*)d_in[7];
    const float* e2_w    = (const float*)d_in[8];
    const float* e2_b    = (const float*)d_in[9];
    const float* conv_b  = (const float*)d_in[10];
    const float* gwih    = (const float*)d_in[11];
    const float* gwhh    = (const float*)d_in[12];
    const float* gbih    = (const float*)d_in[13];
    const float* gbhh    = (const float*)d_in[14];
    const float* lwih    = (const float*)d_in[15];
    const float* lwhh    = (const float*)d_in[16];
    const float* lbih    = (const float*)d_in[17];
    const float* lbhh    = (const float*)d_in[18];

    const int N = NN, E = NE;

    size_t off = 0;
    auto take = [&](size_t bytes) { size_t o = off; off = (off + bytes + 255) & ~(size_t)255; return o; };
    size_t oX    = take((size_t)N * 64 * 4);
    size_t oAgg  = take((size_t)N * 64 * 4);
    size_t oScal = take(4096);
    size_t oH1   = take((size_t)EPAD * 128 * 2);
    size_t oW2T  = take((size_t)4096 * 128 * 2);
    size_t oXb   = take((size_t)N * 64 * 2);
    size_t oB2T  = take((size_t)64 * 64 * 2);
    size_t oIst  = take((size_t)(N + 1) * 4);
    size_t oIc1  = take((size_t)N * 4);
    size_t oIc2  = take((size_t)N * 4);
    size_t oSs   = take((size_t)E * 4);
    size_t oSd   = take((size_t)E * 4);
    size_t oSp   = take((size_t)E * 4);
    size_t needed = off;

    float* outp = (float*)d_out;
    if (ws_size < needed) {
        k_sentinel<<<1, 1, 0, stream>>>(outp);
        return;
    }

    char* wsb = (char*)d_ws;
    float* X    = (float*)(wsb + oX);
    float* agg  = (float*)(wsb + oAgg);
    float* scal = (float*)(wsb + oScal);
    unsigned short* h1b = (unsigned short*)(wsb + oH1);
    unsigned short* w2t = (unsigned short*)(wsb + oW2T);
    unsigned short* Xb  = (unsigned short*)(wsb + oXb);
    unsigned short* b2t = (unsigned short*)(wsb + oB2T);
    int* istart = (int*)(wsb + oIst);
    int* icnt   = (int*)(wsb + oIc1);
    int* icnt2  = (int*)(wsb + oIc2);
    int* ssrc   = (int*)(wsb + oSs);
    int* sdst   = (int*)(wsb + oSd);
    int* spos   = (int*)(wsb + oSp);

    hipMemsetAsync(scal, 0, 4096, stream);
    hipMemsetAsync(icnt, 0, (size_t)N * 4, stream);
    hipMemsetAsync(icnt2, 0, (size_t)N * 4, stream);
    hipMemsetAsync(agg, 0, (size_t)N * 64 * 4, stream);
    hipMemsetAsync(h1b + (size_t)E * 128, 0, (size_t)(EPAD - E) * 128 * 2, stream);

    k_pre<<<PRE_ALL, 256, 0, stream>>>(nfeat, lin0_w, lin0_b, X, Xb,
                                       dst, icnt, e2_w, w2t, e2_b, b2t);
    k_scan<<<1, 1024, 0, stream>>>(icnt, istart);
    k_scatter<<<(E + 255) / 256, 256, 0, stream>>>(src, dst, istart, icnt2, ssrc, sdst, spos, E);
    k_e1<<<(E * 128) / 256, 256, 0, stream>>>(efeat, e1_w, e1_b, spos, h1b);

    for (int r = 0; r < 3; ++r) {
        k_msg<<<dim3(EPAD / 128, 2), 256, 0, stream>>>(Xb, h1b, w2t, b2t, ssrc, sdst, istart, agg);
        k_gru<<<N / 16, 256, 0, stream>>>(agg, istart, conv_b, gwih, gwhh, gbih, gbhh,
                                          X, Xb, (r == 2) ? (outp + 128) : nullptr,
                                          (r < 2) ? 1 : 0);
    }

    for (int it = 0; it < 3; ++it) {
        k_pool<<<128, 256, 0, stream>>>(X, lwih, lwhh, lbih, lbhh, scal, it);
    }
    k_fin<<<1, 128, 0, stream>>>(scal, outp);
}